// Round 1
// baseline (726.723 us; speedup 1.0000x reference)
//
#include <hip/hip_runtime.h>
#include <cmath>

#define Nn    8192
#define INF_  512
#define OUTF  64
#define ALPHA 0.2f

constexpr int RPB = 16;   // rows per block in attention kernel

__device__ __forceinline__ float lrelu(float v) { return v >= 0.0f ? v : ALPHA * v; }

// ---------------------------------------------------------------------------
// Kernel 1: Wh = x @ W  [N, 64];  Wh1 = Wh @ a[:64];  Wh2 = Wh @ a[64:]
// Block: 256 threads = 16 rows x 16 col-groups(4 cols). Grid: N/16 = 512.
// ---------------------------------------------------------------------------
__global__ __launch_bounds__(256) void k1_wh(
    const float* __restrict__ x, const float* __restrict__ W,
    const float* __restrict__ a, float* __restrict__ Wh,
    float* __restrict__ Wh1, float* __restrict__ Wh2)
{
    const int t   = threadIdx.x;
    const int row = blockIdx.x * 16 + (t >> 4);
    const int cg  = (t & 15) << 2;
    const float* __restrict__ xr = x + (size_t)row * INF_;

    float4 acc = make_float4(0.f, 0.f, 0.f, 0.f);
    for (int k = 0; k < INF_; k += 4) {
        const float4 xv = *(const float4*)(xr + k);
        const float* wp = W + (size_t)k * OUTF + cg;
        const float4 w0 = *(const float4*)(wp);
        const float4 w1 = *(const float4*)(wp + OUTF);
        const float4 w2 = *(const float4*)(wp + 2 * OUTF);
        const float4 w3 = *(const float4*)(wp + 3 * OUTF);
        acc.x += xv.x * w0.x + xv.y * w1.x + xv.z * w2.x + xv.w * w3.x;
        acc.y += xv.x * w0.y + xv.y * w1.y + xv.z * w2.y + xv.w * w3.y;
        acc.z += xv.x * w0.z + xv.y * w1.z + xv.z * w2.z + xv.w * w3.z;
        acc.w += xv.x * w0.w + xv.y * w1.w + xv.z * w2.w + xv.w * w3.w;
    }
    *(float4*)(Wh + (size_t)row * OUTF + cg) = acc;

    // partial dot with attention vectors, reduce across the 16 lanes of a row
    float p1 = acc.x * a[cg]        + acc.y * a[cg + 1]
             + acc.z * a[cg + 2]    + acc.w * a[cg + 3];
    float p2 = acc.x * a[OUTF + cg]     + acc.y * a[OUTF + cg + 1]
             + acc.z * a[OUTF + cg + 2] + acc.w * a[OUTF + cg + 3];
    #pragma unroll
    for (int off = 8; off; off >>= 1) {
        p1 += __shfl_xor(p1, off);
        p2 += __shfl_xor(p2, off);
    }
    if ((t & 15) == 0) { Wh1[row] = p1; Wh2[row] = p2; }
}

// ---------------------------------------------------------------------------
// Kernel 2: per block of 16 rows:
//   Phase A (wave-per-row): read adj once, ballot-compress to LDS bitmask,
//            masked max of Wh2 (monotone LeakyReLU trick), exp-sum S.
//   Phase B: per 64-j chunk: att = exp(LRelu(Wh1+Wh2)-m)/S, write to d_out,
//            stage in LDS, accumulate h' = att @ Wh in registers.
//   Epilogue: shuffle+LDS reduce, ELU, write out.
// ---------------------------------------------------------------------------
__global__ __launch_bounds__(256) void k2_attn(
    const int* __restrict__ adj, const float* __restrict__ Wh,
    const float* __restrict__ Wh1, const float* __restrict__ Wh2,
    float* __restrict__ outp, float* __restrict__ att)
{
    __shared__ unsigned long long bm[RPB][Nn / 64];       // 16 KB bitmask
    __shared__ alignas(16) float att_t[RPB][64];          // 4 KB att tile
    __shared__ float sm_m[RPB], sm_is[RPB], sm_h1[RPB];
    __shared__ float4 red[4][16][16];                     // 16 KB reduce scratch

    const int t    = threadIdx.x;
    const int lane = t & 63;
    const int wave = t >> 6;
    const int row0 = blockIdx.x * RPB;

    // ---------------- Phase A ----------------
    for (int rr = wave; rr < RPB; rr += 4) {
        const int row = row0 + rr;
        const int* __restrict__ arow = adj + (size_t)row * Nn;
        const float h1 = Wh1[row];
        float mx = -INFINITY;
        for (int it = 0; it < Nn / 256; ++it) {
            const int j0 = it * 256 + lane;
            #pragma unroll
            for (int c = 0; c < 4; ++c) {
                const int j = j0 + c * 64;
                const int av = arow[j];
                const unsigned long long b = __ballot(av != 0);
                if (lane == 0) bm[rr][it * 4 + c] = b;
                const float w2 = Wh2[j];
                if (av != 0) mx = fmaxf(mx, w2);
            }
        }
        #pragma unroll
        for (int off = 32; off; off >>= 1) mx = fmaxf(mx, __shfl_xor(mx, off));
        const float K = lrelu(h1 + mx);   // row max of masked logits (monotone)

        float S = 0.0f;
        for (int it = 0; it < Nn / 64; ++it) {
            const unsigned long long b = bm[rr][it];
            const float e  = lrelu(h1 + Wh2[it * 64 + lane]);
            const float ex = __expf(e - K);
            if ((b >> lane) & 1ull) S += ex;      // select AFTER exp: inf discarded
        }
        #pragma unroll
        for (int off = 32; off; off >>= 1) S += __shfl_xor(S, off);
        if (lane == 0) { sm_m[rr] = K; sm_is[rr] = 1.0f / S; sm_h1[rr] = h1; }
    }
    __syncthreads();

    // row constants for this thread's 4 rows (rr = wave + 4k)
    float h1r[4], mr[4], isr[4];
    #pragma unroll
    for (int k = 0; k < 4; ++k) {
        const int rr = wave + 4 * k;
        h1r[k] = sm_h1[rr]; mr[k] = sm_m[rr]; isr[k] = sm_is[rr];
    }

    const int cg  = t & 15;          // col group (4 cols)
    const int jj0 = (t >> 4) << 2;   // this thread's 4 consecutive js in chunk

    float4 acc[16];
    #pragma unroll
    for (int r = 0; r < 16; ++r) acc[r] = make_float4(0.f, 0.f, 0.f, 0.f);

    // ---------------- Phase B ----------------
    for (int jb = 0; jb < Nn; jb += 64) {
        const float w2v = Wh2[jb + lane];
        const int widx  = jb >> 6;
        #pragma unroll
        for (int k = 0; k < 4; ++k) {
            const int rr = wave + 4 * k;
            const unsigned long long b = bm[rr][widx];
            const int bit = (int)((b >> lane) & 1ull);
            const float e  = lrelu(h1r[k] + w2v);
            const float av = bit ? __expf(e - mr[k]) * isr[k] : 0.0f;
            att[(size_t)(row0 + rr) * Nn + jb + lane] = av;   // coalesced 256B
            att_t[rr][lane] = av;                             // conflict-free
        }
        __syncthreads();

        // PV: 4 js x 16 rows x 4 cols per thread
        const float* whp = Wh + (size_t)(jb + jj0) * OUTF + (cg << 2);
        const float4 wv0 = *(const float4*)(whp);
        const float4 wv1 = *(const float4*)(whp + OUTF);
        const float4 wv2 = *(const float4*)(whp + 2 * OUTF);
        const float4 wv3 = *(const float4*)(whp + 3 * OUTF);
        #pragma unroll
        for (int r = 0; r < 16; ++r) {
            const float4 av4 = *(const float4*)&att_t[r][jj0];  // bcast b128
            acc[r].x += av4.x * wv0.x + av4.y * wv1.x + av4.z * wv2.x + av4.w * wv3.x;
            acc[r].y += av4.x * wv0.y + av4.y * wv1.y + av4.z * wv2.y + av4.w * wv3.y;
            acc[r].z += av4.x * wv0.z + av4.y * wv1.z + av4.z * wv2.z + av4.w * wv3.z;
            acc[r].w += av4.x * wv0.w + av4.y * wv1.w + av4.z * wv2.w + av4.w * wv3.w;
        }
        __syncthreads();
    }

    // ---------------- Epilogue: reduce over the 16 j-slot groups ----------------
    #pragma unroll
    for (int r = 0; r < 16; ++r) {
        float4 v = acc[r];
        #pragma unroll
        for (int off = 16; off <= 32; off <<= 1) {
            v.x += __shfl_xor(v.x, off);
            v.y += __shfl_xor(v.y, off);
            v.z += __shfl_xor(v.z, off);
            v.w += __shfl_xor(v.w, off);
        }
        acc[r] = v;
    }
    if (lane < 16) {
        #pragma unroll
        for (int r = 0; r < 16; ++r) red[wave][lane][r] = acc[r];
    }
    __syncthreads();
    {
        const int r = t >> 4;
        const int c = t & 15;
        float4 h  = red[0][c][r];
        const float4 hb = red[1][c][r];
        const float4 hc = red[2][c][r];
        const float4 hd = red[3][c][r];
        h.x += hb.x + hc.x + hd.x;
        h.y += hb.y + hc.y + hd.y;
        h.z += hb.z + hc.z + hd.z;
        h.w += hb.w + hc.w + hd.w;
        h.x = h.x > 0.f ? h.x : expm1f(h.x);
        h.y = h.y > 0.f ? h.y : expm1f(h.y);
        h.z = h.z > 0.f ? h.z : expm1f(h.z);
        h.w = h.w > 0.f ? h.w : expm1f(h.w);
        *(float4*)(outp + (size_t)(row0 + r) * OUTF + (c << 2)) = h;
    }
}

// ---------------------------------------------------------------------------
extern "C" void kernel_launch(void* const* d_in, const int* in_sizes, int n_in,
                              void* d_out, int out_size, void* d_ws, size_t ws_size,
                              hipStream_t stream)
{
    const float* x   = (const float*)d_in[0];
    const int*   adj = (const int*)d_in[1];
    const float* W   = (const float*)d_in[2];
    const float* a   = (const float*)d_in[3];

    float* outp = (float*)d_out;                       // [N, 64]
    float* att  = outp + (size_t)Nn * OUTF;            // [N, N]

    float* Wh  = (float*)d_ws;                         // 2 MB
    float* Wh1 = Wh + (size_t)Nn * OUTF;               // 32 KB
    float* Wh2 = Wh1 + Nn;                             // 32 KB

    hipLaunchKernelGGL(k1_wh, dim3(Nn / 16), dim3(256), 0, stream,
                       x, W, a, Wh, Wh1, Wh2);
    hipLaunchKernelGGL(k2_attn, dim3(Nn / RPB), dim3(256), 0, stream,
                       adj, Wh, Wh1, Wh2, outp, att);
}

// Round 2
// 356.281 us; speedup vs baseline: 2.0397x; 2.0397x over previous
//
#include <hip/hip_runtime.h>
#include <cmath>

#define Nn    8192
#define INF_  512
#define OUTF  64
#define ALPHA 0.2f

__device__ __forceinline__ float lrelu(float v) { return v >= 0.0f ? v : ALPHA * v; }

// ---------------------------------------------------------------------------
// Kernel 1: Wh = x @ W  [N, 64];  Wh1 = Wh @ a[:64];  Wh2 = Wh @ a[64:]
// Block: 256 threads = 16 rows x 16 col-groups(4 cols). Grid: N/16 = 512.
// ---------------------------------------------------------------------------
__global__ __launch_bounds__(256) void k1_wh(
    const float* __restrict__ x, const float* __restrict__ W,
    const float* __restrict__ a, float* __restrict__ Wh,
    float* __restrict__ Wh1, float* __restrict__ Wh2)
{
    const int t   = threadIdx.x;
    const int row = blockIdx.x * 16 + (t >> 4);
    const int cg  = (t & 15) << 2;
    const float* __restrict__ xr = x + (size_t)row * INF_;

    float4 acc = make_float4(0.f, 0.f, 0.f, 0.f);
    for (int k = 0; k < INF_; k += 4) {
        const float4 xv = *(const float4*)(xr + k);
        const float* wp = W + (size_t)k * OUTF + cg;
        const float4 w0 = *(const float4*)(wp);
        const float4 w1 = *(const float4*)(wp + OUTF);
        const float4 w2 = *(const float4*)(wp + 2 * OUTF);
        const float4 w3 = *(const float4*)(wp + 3 * OUTF);
        acc.x += xv.x * w0.x + xv.y * w1.x + xv.z * w2.x + xv.w * w3.x;
        acc.y += xv.x * w0.y + xv.y * w1.y + xv.z * w2.y + xv.w * w3.y;
        acc.z += xv.x * w0.z + xv.y * w1.z + xv.z * w2.z + xv.w * w3.z;
        acc.w += xv.x * w0.w + xv.y * w1.w + xv.z * w2.w + xv.w * w3.w;
    }
    *(float4*)(Wh + (size_t)row * OUTF + cg) = acc;

    float p1 = acc.x * a[cg]        + acc.y * a[cg + 1]
             + acc.z * a[cg + 2]    + acc.w * a[cg + 3];
    float p2 = acc.x * a[OUTF + cg]     + acc.y * a[OUTF + cg + 1]
             + acc.z * a[OUTF + cg + 2] + acc.w * a[OUTF + cg + 3];
    #pragma unroll
    for (int off = 8; off; off >>= 1) {
        p1 += __shfl_xor(p1, off);
        p2 += __shfl_xor(p2, off);
    }
    if ((t & 15) == 0) { Wh1[row] = p1; Wh2[row] = p2; }
}

// ---------------------------------------------------------------------------
// Kernel 2a: wave-per-row adjacency scan.
//   Sweep 1: read adj (268 MB, streaming), ballot-compress to bitmask,
//            masked max of Wh2 (monotone LeakyReLU trick).
//   Sweep 2: exp-sum S from bitmask (LDS) + Wh2 (L1).
//   Emits: bm_g [N][128] u64 (8 MB), m_g[N], is_g[N].
// Block 256 = 4 waves = 4 rows; grid N/4 = 2048 -> 8 blocks/CU.
// ---------------------------------------------------------------------------
__global__ __launch_bounds__(256) void k2a_mask(
    const int* __restrict__ adj, const float* __restrict__ Wh1,
    const float* __restrict__ Wh2, unsigned long long* __restrict__ bm_g,
    float* __restrict__ m_g, float* __restrict__ is_g)
{
    __shared__ unsigned long long bm[4][Nn / 64];   // 4 KB
    const int lane = threadIdx.x & 63;
    const int wv   = threadIdx.x >> 6;
    const int row  = blockIdx.x * 4 + wv;
    const int* __restrict__ arow = adj + (size_t)row * Nn;

    float mx = -INFINITY;
    for (int it = 0; it < Nn / 256; ++it) {
        #pragma unroll
        for (int c = 0; c < 4; ++c) {
            const int j  = it * 256 + c * 64 + lane;
            const int av = __builtin_nontemporal_load(&arow[j]);
            const unsigned long long b = __ballot(av != 0);
            if (lane == 0) bm[wv][it * 4 + c] = b;
            const float w2 = Wh2[j];
            if (av) mx = fmaxf(mx, w2);
        }
    }
    #pragma unroll
    for (int off = 32; off; off >>= 1) mx = fmaxf(mx, __shfl_xor(mx, off));

    __syncthreads();   // publish bm (lane0 writes -> all lanes read)

    const float h1 = Wh1[row];
    const float K  = lrelu(h1 + mx);
    float S = 0.0f;
    for (int w = 0; w < Nn / 64; ++w) {
        const unsigned long long b = bm[wv][w];
        const float e  = lrelu(h1 + Wh2[w * 64 + lane]);
        const float ex = __expf(e - K);
        if ((b >> lane) & 1ull) S += ex;
    }
    #pragma unroll
    for (int off = 32; off; off >>= 1) S += __shfl_xor(S, off);
    if (lane == 0) { m_g[row] = K; is_g[row] = 1.0f / S; }

    unsigned long long* __restrict__ dst = bm_g + (size_t)row * (Nn / 64);
    #pragma unroll
    for (int w = lane; w < Nn / 64; w += 64) dst[w] = bm[wv][w];
}

// ---------------------------------------------------------------------------
// Kernel 2b: att materialization + PV + ELU.
// 512 threads = 8 waves; 16 rows/block; grid N/16 = 512; j-chunk = 128.
// Producer: wave w computes att for rows {w, w+8} (bit ? exp*is : 0),
//           writes global (nontemporal) + LDS tile.
// PV: thread (cg = t&31 -> 2 cols, jg = t>>5 -> 8 js) accumulates
//     acc[16 rows] float2; b128 LDS reads of att tile, register Wh.
// Epilogue: xor-32 shuffle + LDS reduce over 8 waves, ELU, store.
// ---------------------------------------------------------------------------
__global__ __launch_bounds__(512) void k2b_pv(
    const float* __restrict__ Wh, const float* __restrict__ Wh1,
    const float* __restrict__ Wh2, const unsigned long long* __restrict__ bm_g,
    const float* __restrict__ m_g, const float* __restrict__ is_g,
    float* __restrict__ outp, float* __restrict__ att)
{
    __shared__ alignas(16) char smem[32768];
    float  (*att_t)[128]    = (float (*)[128])smem;          // 16x128 = 8 KB
    float2 (*red)[16][32]   = (float2 (*)[16][32])smem;      // 8x16x32 = 32 KB

    const int t    = threadIdx.x;
    const int lane = t & 63;
    const int wave = t >> 6;
    const int row0 = blockIdx.x * 16;

    const int rA = wave, rB = wave + 8;
    const float h1A = Wh1[row0 + rA], mA = m_g[row0 + rA], isA = is_g[row0 + rA];
    const float h1B = Wh1[row0 + rB], mB = m_g[row0 + rB], isB = is_g[row0 + rB];
    const unsigned long long* __restrict__ bmA = bm_g + (size_t)(row0 + rA) * (Nn / 64);
    const unsigned long long* __restrict__ bmB = bm_g + (size_t)(row0 + rB) * (Nn / 64);

    const int cg  = t & 31;          // 2 cols: cg*2, cg*2+1
    const int jg  = t >> 5;          // 16 groups x 8 js
    const int jj0 = jg * 8;

    float2 acc[16];
    #pragma unroll
    for (int r = 0; r < 16; ++r) acc[r] = make_float2(0.f, 0.f);

    for (int jb = 0; jb < Nn; jb += 128) {
        #pragma unroll
        for (int h = 0; h < 2; ++h) {
            const int j  = jb + h * 64 + lane;
            const int wi = (jb >> 6) + h;
            const float w2 = Wh2[j];
            const unsigned long long bA = bmA[wi];
            const unsigned long long bB = bmB[wi];
            const float eA = lrelu(h1A + w2);
            const float eB = lrelu(h1B + w2);
            const float vA = ((bA >> lane) & 1ull) ? __expf(eA - mA) * isA : 0.0f;
            const float vB = ((bB >> lane) & 1ull) ? __expf(eB - mB) * isB : 0.0f;
            __builtin_nontemporal_store(vA, &att[(size_t)(row0 + rA) * Nn + j]);
            __builtin_nontemporal_store(vB, &att[(size_t)(row0 + rB) * Nn + j]);
            att_t[rA][h * 64 + lane] = vA;
            att_t[rB][h * 64 + lane] = vB;
        }
        __syncthreads();

        float2 wreg[8];
        #pragma unroll
        for (int q = 0; q < 8; ++q)
            wreg[q] = *(const float2*)(Wh + (size_t)(jb + jj0 + q) * OUTF + cg * 2);
        #pragma unroll
        for (int r = 0; r < 16; ++r) {
            const float4 a0 = *(const float4*)&att_t[r][jj0];
            const float4 a1 = *(const float4*)&att_t[r][jj0 + 4];
            acc[r].x += a0.x * wreg[0].x + a0.y * wreg[1].x + a0.z * wreg[2].x + a0.w * wreg[3].x
                      + a1.x * wreg[4].x + a1.y * wreg[5].x + a1.z * wreg[6].x + a1.w * wreg[7].x;
            acc[r].y += a0.x * wreg[0].y + a0.y * wreg[1].y + a0.z * wreg[2].y + a0.w * wreg[3].y
                      + a1.x * wreg[4].y + a1.y * wreg[5].y + a1.z * wreg[6].y + a1.w * wreg[7].y;
        }
        __syncthreads();
    }

    // reduce over jg: within wave the two jg's differ at lane bit 5
    #pragma unroll
    for (int r = 0; r < 16; ++r) {
        acc[r].x += __shfl_xor(acc[r].x, 32);
        acc[r].y += __shfl_xor(acc[r].y, 32);
    }
    if (lane < 32) {
        #pragma unroll
        for (int r = 0; r < 16; ++r) red[wave][r][lane] = acc[r];
    }
    __syncthreads();
    {
        const int r = t >> 5;
        const int c = t & 31;
        float2 h = red[0][r][c];
        #pragma unroll
        for (int w = 1; w < 8; ++w) { const float2 p = red[w][r][c]; h.x += p.x; h.y += p.y; }
        h.x = h.x > 0.f ? h.x : expm1f(h.x);
        h.y = h.y > 0.f ? h.y : expm1f(h.y);
        *(float2*)(outp + (size_t)(row0 + r) * OUTF + c * 2) = h;
    }
}

// ---------------------------------------------------------------------------
extern "C" void kernel_launch(void* const* d_in, const int* in_sizes, int n_in,
                              void* d_out, int out_size, void* d_ws, size_t ws_size,
                              hipStream_t stream)
{
    const float* x   = (const float*)d_in[0];
    const int*   adj = (const int*)d_in[1];
    const float* W   = (const float*)d_in[2];
    const float* a   = (const float*)d_in[3];

    float* outp = (float*)d_out;                       // [N, 64]
    float* att  = outp + (size_t)Nn * OUTF;            // [N, N]

    // workspace layout (~10.2 MB)
    float* Wh  = (float*)d_ws;                         // 2 MB
    float* Wh1 = Wh + (size_t)Nn * OUTF;               // 32 KB
    float* Wh2 = Wh1 + Nn;                             // 32 KB
    float* m_g = Wh2 + Nn;                             // 32 KB
    float* is_g = m_g + Nn;                            // 32 KB
    unsigned long long* bm_g = (unsigned long long*)(is_g + Nn);  // 8 MB

    hipLaunchKernelGGL(k1_wh,   dim3(Nn / 16), dim3(256), 0, stream,
                       x, W, a, Wh, Wh1, Wh2);
    hipLaunchKernelGGL(k2a_mask, dim3(Nn / 4), dim3(256), 0, stream,
                       adj, Wh1, Wh2, bm_g, m_g, is_g);
    hipLaunchKernelGGL(k2b_pv,  dim3(Nn / 16), dim3(512), 0, stream,
                       Wh, Wh1, Wh2, bm_g, m_g, is_g, outp, att);
}

// Round 3
// 202.954 us; speedup vs baseline: 3.5807x; 1.7555x over previous
//
#include <hip/hip_runtime.h>
#include <cmath>

#define Nn    8192
#define INF_  512
#define OUTF  64

typedef __attribute__((ext_vector_type(4))) int   i4;
typedef __attribute__((ext_vector_type(2))) float f2;
typedef __attribute__((ext_vector_type(4))) float f4v;
typedef __attribute__((ext_vector_type(8))) short s8;
typedef __attribute__((ext_vector_type(4))) float f32x4;

__device__ __forceinline__ float lrelu(float v) { return fmaxf(v, 0.2f * v); }

// float -> bf16 (RNE) as raw ushort
__device__ __forceinline__ unsigned short f2bf(float f) {
    unsigned int u = __float_as_uint(f);
    u = (u + 0x7FFFu + ((u >> 16) & 1u)) >> 16;
    return (unsigned short)u;
}

// ---------------------------------------------------------------------------
// Kernel 1: Wh = x @ W (kept in regs); emits WhT (bf16, [64][8192]) for the
// MFMA B operand, plus Wh1 = Wh@a[:64], Wh2 = Wh@a[64:].
// Block: 256 thr = 16 rows x 16 colgroups(4). Grid: N/16 = 512.
// ---------------------------------------------------------------------------
__global__ __launch_bounds__(256) void k1_wh(
    const float* __restrict__ x, const float* __restrict__ W,
    const float* __restrict__ a, unsigned short* __restrict__ WhT,
    float* __restrict__ Wh1, float* __restrict__ Wh2)
{
    const int t   = threadIdx.x;
    const int row = blockIdx.x * 16 + (t >> 4);
    const int cg  = (t & 15) << 2;
    const float* __restrict__ xr = x + (size_t)row * INF_;

    float4 acc = make_float4(0.f, 0.f, 0.f, 0.f);
    for (int k = 0; k < INF_; k += 4) {
        const float4 xv = *(const float4*)(xr + k);
        const float* wp = W + (size_t)k * OUTF + cg;
        const float4 w0 = *(const float4*)(wp);
        const float4 w1 = *(const float4*)(wp + OUTF);
        const float4 w2 = *(const float4*)(wp + 2 * OUTF);
        const float4 w3 = *(const float4*)(wp + 3 * OUTF);
        acc.x += xv.x * w0.x + xv.y * w1.x + xv.z * w2.x + xv.w * w3.x;
        acc.y += xv.x * w0.y + xv.y * w1.y + xv.z * w2.y + xv.w * w3.y;
        acc.z += xv.x * w0.z + xv.y * w1.z + xv.z * w2.z + xv.w * w3.z;
        acc.w += xv.x * w0.w + xv.y * w1.w + xv.z * w2.w + xv.w * w3.w;
    }
    WhT[(size_t)(cg + 0) * Nn + row] = f2bf(acc.x);
    WhT[(size_t)(cg + 1) * Nn + row] = f2bf(acc.y);
    WhT[(size_t)(cg + 2) * Nn + row] = f2bf(acc.z);
    WhT[(size_t)(cg + 3) * Nn + row] = f2bf(acc.w);

    float p1 = acc.x * a[cg]        + acc.y * a[cg + 1]
             + acc.z * a[cg + 2]    + acc.w * a[cg + 3];
    float p2 = acc.x * a[OUTF + cg]     + acc.y * a[OUTF + cg + 1]
             + acc.z * a[OUTF + cg + 2] + acc.w * a[OUTF + cg + 3];
    #pragma unroll
    for (int off = 8; off; off >>= 1) {
        p1 += __shfl_xor(p1, off);
        p2 += __shfl_xor(p2, off);
    }
    if ((t & 15) == 0) { Wh1[row] = p1; Wh2[row] = p2; }
}

// ---------------------------------------------------------------------------
// Kernel 2a: wave-per-row adjacency scan, dwordx4 loads (4 js/lane).
// nibble per lane -> u64 word packed via 4 xor-shuffle ORs.
// Emits bm_g [N][128] u64, m_g[N] (row max K), is_g[N] (1/S).
// Block 256 = 4 rows; grid N/4 = 2048 (8 blocks/CU).
// ---------------------------------------------------------------------------
__global__ __launch_bounds__(256) void k2a_mask(
    const int* __restrict__ adj, const float* __restrict__ Wh1,
    const float* __restrict__ Wh2, unsigned long long* __restrict__ bm_g,
    float* __restrict__ m_g, float* __restrict__ is_g)
{
    __shared__ unsigned long long bm[4][Nn / 64];   // 4 KB
    const int lane = threadIdx.x & 63;
    const int wv   = threadIdx.x >> 6;
    const int row  = blockIdx.x * 4 + wv;
    const int* __restrict__ arow = adj + (size_t)row * Nn;

    float mx = -INFINITY;
    for (int jb = 0; jb < Nn; jb += 256) {
        const i4  av = __builtin_nontemporal_load((const i4*)(arow + jb) + lane);
        const f4v w4 = *((const f4v*)(Wh2 + jb) + lane);
        const int nib = (av.x != 0 ? 1 : 0) | (av.y != 0 ? 2 : 0)
                      | (av.z != 0 ? 4 : 0) | (av.w != 0 ? 8 : 0);
        const float m0 = av.x ? w4.x : -INFINITY;
        const float m1 = av.y ? w4.y : -INFINITY;
        const float m2 = av.z ? w4.z : -INFINITY;
        const float m3 = av.w ? w4.w : -INFINITY;
        mx = fmaxf(mx, fmaxf(fmaxf(m0, m1), fmaxf(m2, m3)));

        unsigned long long part = (unsigned long long)nib << ((lane & 15) * 4);
        part |= __shfl_xor(part, 1);
        part |= __shfl_xor(part, 2);
        part |= __shfl_xor(part, 4);
        part |= __shfl_xor(part, 8);
        if ((lane & 15) == 0) bm[wv][(jb >> 6) + (lane >> 4)] = part;
    }
    #pragma unroll
    for (int off = 32; off; off >>= 1) mx = fmaxf(mx, __shfl_xor(mx, off));

    __syncthreads();

    const float h1 = Wh1[row];
    const float K  = lrelu(h1 + mx);
    float S = 0.0f;
    for (int w = 0; w < Nn / 64; ++w) {
        const unsigned long long b = bm[wv][w];
        const float e  = lrelu(h1 + Wh2[w * 64 + lane]);
        const float ex = __expf(e - K);
        if ((b >> lane) & 1ull) S += ex;
    }
    #pragma unroll
    for (int off = 32; off; off >>= 1) S += __shfl_xor(S, off);
    if (lane == 0) { m_g[row] = K; is_g[row] = 1.0f / S; }

    unsigned long long* __restrict__ dst = bm_g + (size_t)row * (Nn / 64);
    #pragma unroll
    for (int w = lane; w < Nn / 64; w += 64) dst[w] = bm[wv][w];
}

// ---------------------------------------------------------------------------
// Kernel 2b: att materialization (f32 global, exact) + bf16 LDS tile +
// MFMA PV + ELU.  512 thr = 8 waves; 16 rows/block; grid 512; chunk = 128 js.
// Producer: wave w -> rows {2w, 2w+1}, lane covers js {2*lane, 2*lane+1}.
// LDS tile [16][128] bf16, XOR-swizzled (byte ^= (row&7)<<4).
// PV: wave w -> coltile ct=w&3, k-half kh=w>>2; per chunk 2x
//     mfma_f32_16x16x32_bf16 (A = att tile b128, B = WhT global b128).
// Epilogue: kh-pair reduce via LDS, ELU, store.
// ---------------------------------------------------------------------------
__global__ __launch_bounds__(512) void k2b_pv(
    const unsigned short* __restrict__ WhT, const float* __restrict__ Wh1,
    const float* __restrict__ Wh2, const unsigned long long* __restrict__ bm_g,
    const float* __restrict__ m_g, const float* __restrict__ is_g,
    float* __restrict__ outp, float* __restrict__ att)
{
    __shared__ alignas(16) unsigned short att_t[2][16 * 128];  // 8 KB
    __shared__ float red[4][16][16];                           // 4 KB

    const int t    = threadIdx.x;
    const int lane = t & 63;
    const int w    = t >> 6;
    const int row0 = blockIdx.x * 16;

    const int rA = 2 * w, rB = 2 * w + 1;
    const float h1A = Wh1[row0 + rA], mA = m_g[row0 + rA], isA = is_g[row0 + rA];
    const float h1B = Wh1[row0 + rB], mB = m_g[row0 + rB], isB = is_g[row0 + rB];
    const unsigned long long* __restrict__ bmA = bm_g + (size_t)(row0 + rA) * (Nn / 64);
    const unsigned long long* __restrict__ bmB = bm_g + (size_t)(row0 + rB) * (Nn / 64);

    const int ct = w & 3;    // col tile (16 cols)
    const int kh = w >> 2;   // k half (2 of 4 ksteps per chunk)
    f32x4 acc = {0.f, 0.f, 0.f, 0.f};

    const int j2   = lane * 2;
    const int wsub = j2 >> 6;        // which 64-wide word inside the chunk
    const int bit0 = j2 & 63;

    auto produce = [&](int c, int b) {
        const int jb = c * 128;
        const f2 w2 = *((const f2*)(Wh2 + jb) + lane);
        const int wi = (jb >> 6) + wsub;
        {
            const unsigned long long bA = bmA[wi];
            const float e0 = lrelu(h1A + w2.x);
            const float e1 = lrelu(h1A + w2.y);
            const float v0 = ((bA >> bit0) & 1ull)       ? __expf(e0 - mA) * isA : 0.f;
            const float v1 = ((bA >> (bit0 + 1)) & 1ull) ? __expf(e1 - mA) * isA : 0.f;
            f2 st; st.x = v0; st.y = v1;
            __builtin_nontemporal_store(st, (f2*)(att + (size_t)(row0 + rA) * Nn + jb) + lane);
            const unsigned int pk = (unsigned)f2bf(v0) | ((unsigned)f2bf(v1) << 16);
            int byte = rA * 256 + j2 * 2;  byte ^= (rA & 7) << 4;
            *(unsigned int*)((char*)att_t[b] + byte) = pk;
        }
        {
            const unsigned long long bB = bmB[wi];
            const float e0 = lrelu(h1B + w2.x);
            const float e1 = lrelu(h1B + w2.y);
            const float v0 = ((bB >> bit0) & 1ull)       ? __expf(e0 - mB) * isB : 0.f;
            const float v1 = ((bB >> (bit0 + 1)) & 1ull) ? __expf(e1 - mB) * isB : 0.f;
            f2 st; st.x = v0; st.y = v1;
            __builtin_nontemporal_store(st, (f2*)(att + (size_t)(row0 + rB) * Nn + jb) + lane);
            const unsigned int pk = (unsigned)f2bf(v0) | ((unsigned)f2bf(v1) << 16);
            int byte = rB * 256 + j2 * 2;  byte ^= (rB & 7) << 4;
            *(unsigned int*)((char*)att_t[b] + byte) = pk;
        }
    };

    const int arow = lane & 15;          // A row this lane reads
    const int agrp = lane >> 4;          // k-subgroup
    auto domfma = [&](int c, int b) {
        const int jb = c * 128;
        #pragma unroll
        for (int s = 0; s < 2; ++s) {
            const int ks = kh * 2 + s;
            int byte = arow * 256 + ks * 64 + agrp * 16;
            byte ^= (arow & 7) << 4;
            const s8 afrag = *(const s8*)((char*)att_t[b] + byte);
            const s8 bfrag = *(const s8*)(WhT + (size_t)(ct * 16 + arow) * Nn
                                          + jb + ks * 32 + agrp * 8);
            acc = __builtin_amdgcn_mfma_f32_16x16x32_bf16(afrag, bfrag, acc, 0, 0, 0);
        }
    };

    produce(0, 0);
    __syncthreads();
    for (int c = 0; c < Nn / 128 - 1; ++c) {
        produce(c + 1, (c + 1) & 1);
        domfma(c, c & 1);
        __syncthreads();
    }
    domfma(Nn / 128 - 1, (Nn / 128 - 1) & 1);

    __syncthreads();
    if (kh == 1) {
        #pragma unroll
        for (int q = 0; q < 4; ++q) red[ct][agrp * 4 + q][arow] = acc[q];
    }
    __syncthreads();
    if (kh == 0) {
        #pragma unroll
        for (int q = 0; q < 4; ++q) {
            float v = acc[q] + red[ct][agrp * 4 + q][arow];
            v = v > 0.f ? v : expm1f(v);
            outp[(size_t)(row0 + agrp * 4 + q) * OUTF + ct * 16 + arow] = v;
        }
    }
}

// ---------------------------------------------------------------------------
extern "C" void kernel_launch(void* const* d_in, const int* in_sizes, int n_in,
                              void* d_out, int out_size, void* d_ws, size_t ws_size,
                              hipStream_t stream)
{
    const float* x   = (const float*)d_in[0];
    const int*   adj = (const int*)d_in[1];
    const float* W   = (const float*)d_in[2];
    const float* a   = (const float*)d_in[3];

    float* outp = (float*)d_out;                       // [N, 64]
    float* att  = outp + (size_t)Nn * OUTF;            // [N, N]

    // workspace layout (~9.2 MB)
    float* Wh1 = (float*)d_ws;                          // 32 KB
    float* Wh2 = Wh1 + Nn;                              // 32 KB
    float* m_g = Wh2 + Nn;                              // 32 KB
    float* is_g = m_g + Nn;                             // 32 KB
    unsigned short* WhT = (unsigned short*)(is_g + Nn); // 1 MB bf16 [64][8192]
    unsigned long long* bm_g = (unsigned long long*)(WhT + (size_t)OUTF * Nn); // 8 MB

    hipLaunchKernelGGL(k1_wh,    dim3(Nn / 16), dim3(256), 0, stream,
                       x, W, a, WhT, Wh1, Wh2);
    hipLaunchKernelGGL(k2a_mask, dim3(Nn / 4),  dim3(256), 0, stream,
                       adj, Wh1, Wh2, bm_g, m_g, is_g);
    hipLaunchKernelGGL(k2b_pv,   dim3(Nn / 16), dim3(512), 0, stream,
                       WhT, Wh1, Wh2, bm_g, m_g, is_g, outp, att);
}